// Round 8
// baseline (529.225 us; speedup 1.0000x reference)
//
#include <hip/hip_runtime.h>
#include <math.h>

// Problem constants
#define NPTS   16384      // 16*32*32 points
#define NE     8192       // codebook entries
#define DIM    256        // embedding dim
#define BIMG   16
#define HW     1024       // 32*32
#define ZQ_N   4194304
#define OFF_LOSS  4194304
#define OFF_PERP  4194305
#define OFF_IDX   4194306

#define NT     64                   // code tiles of 128 (= GEMM BN)
#define NUNITS (NPTS * NT)          // 1,048,576 (p,T) units
#define KSLOT  4                    // bounded slots per unit
#define SBUF   768                  // per-block LDS side buffer (u32)
#define OCAP   650000               // global side-list capacity
#define SJCAP  2000000              // singles job capacity (aliases zhT, 8MB)
#define FJCAP  1048576              // full-tile job capacity (aliases eh, 4MB)

typedef short s16x8 __attribute__((ext_vector_type(8)));
typedef float f32x4 __attribute__((ext_vector_type(4)));

// f32 multiply that can NOT be contracted into an FMA (numpy rounds zf*zf).
__device__ __forceinline__ float mul_rn(float a, float b) {
    float r;
    asm("v_mul_f32 %0, %1, %2" : "=v"(r) : "v"(a), "v"(b));
    return r;
}

// RNE float -> bf16 bits
__device__ __forceinline__ unsigned short f2bf(float f) {
    unsigned int u = __float_as_uint(f);
    return (unsigned short)((u + 0x7fffu + ((u >> 16) & 1u)) >> 16);
}

__device__ __forceinline__ void gl_lds16(const void* g, void* l) {
    __builtin_amdgcn_global_load_lds(
        (const __attribute__((address_space(1))) void*)g,
        (__attribute__((address_space(3))) void*)l, 16, 0, 0);
}

// exact f32 chain dot (bit-identical to validated reference semantics) + min
__device__ __forceinline__ void dot_min(const float* __restrict__ zp,
                                        const float* __restrict__ e,
                                        float zq, int p, int c,
                                        unsigned long long* __restrict__ pbest) {
    const float4* zp4 = (const float4*)zp;
    const float4* ep = (const float4*)(e + (size_t)c * 256);
    float a = 0.f;
    for (int k4 = 0; k4 < 64; ++k4) {
        float4 zv = zp4[k4];
        float4 ev = ep[k4];
        a = fmaf(zv.x, ev.x, a);   // k ascending, single accumulator,
        a = fmaf(zv.y, ev.y, a);   // fused per step (validated round 2)
        a = fmaf(zv.z, ev.z, a);
        a = fmaf(zv.w, ev.w, a);
    }
    float d = zq - 2.0f * a;
    unsigned long long key =
        ((unsigned long long)__float_as_uint(d) << 32) | (unsigned int)c;
    atomicMin(pbest + p, key);
}

// ---------------------------------------------------------------------------
// K_prep_z: z[b][k][hw] -> zT[p][k] f32 (into d_out z_q region) + zhT bf16
// ---------------------------------------------------------------------------
__global__ __launch_bounds__(256)
void k_prep_z(const float* __restrict__ z, float* __restrict__ zT,
              unsigned short* __restrict__ zhT) {
    int bid = blockIdx.x;
    int ht = bid & 15, kt = (bid >> 4) & 3, b = bid >> 6;
    int k0 = kt * 64, hw0 = ht * 64;
    __shared__ float lt[64][65];
    int t = threadIdx.x;
    {
        int kr = t >> 2, j4 = (t & 3) * 16;
        const float* src = z + ((size_t)b * 256 + k0 + kr) * 1024 + hw0 + j4;
        #pragma unroll
        for (int q = 0; q < 4; ++q) {
            float4 v = *(const float4*)(src + q * 4);
            lt[kr][j4 + q * 4 + 0] = v.x; lt[kr][j4 + q * 4 + 1] = v.y;
            lt[kr][j4 + q * 4 + 2] = v.z; lt[kr][j4 + q * 4 + 3] = v.w;
        }
    }
    __syncthreads();
    {
        int pr = t >> 2, kb = (t & 3) * 16;
        size_t p = (size_t)b * 1024 + hw0 + pr;
        float vals[16];
        #pragma unroll
        for (int i = 0; i < 16; ++i) vals[i] = lt[kb + i][pr];
        float* dst = zT + p * 256 + k0 + kb;
        #pragma unroll
        for (int q = 0; q < 4; ++q)
            *(float4*)(dst + q * 4) = make_float4(vals[q*4], vals[q*4+1],
                                                  vals[q*4+2], vals[q*4+3]);
        unsigned short* hd = zhT + p * 256 + k0 + kb;
        #pragma unroll
        for (int q = 0; q < 4; ++q) {
            ushort4 h;
            h.x = f2bf(vals[q*4]);   h.y = f2bf(vals[q*4+1]);
            h.z = f2bf(vals[q*4+2]); h.w = f2bf(vals[q*4+3]);
            *(ushort4*)(hd + q * 4) = h;
        }
    }
}

// ---------------------------------------------------------------------------
// K_prep_e: e[c][k] f32 -> eh bf16
// ---------------------------------------------------------------------------
__global__ void k_prep_e(const float* __restrict__ e, unsigned short* __restrict__ eh) {
    size_t i = ((size_t)blockIdx.x * 256 + threadIdx.x) * 16;
    #pragma unroll
    for (int q = 0; q < 4; ++q) {
        float4 v = *(const float4*)(e + i + q * 4);
        ushort4 h;
        h.x = f2bf(v.x); h.y = f2bf(v.y); h.z = f2bf(v.z); h.w = f2bf(v.w);
        *(ushort4*)(eh + i + q * 4) = h;
    }
}

// ---------------------------------------------------------------------------
// K_zsq: numpy-pairwise ||z||^2 (validated) + sound margin + 32/marg
// ---------------------------------------------------------------------------
__global__ void k_zsq(const float* __restrict__ zT, float* __restrict__ zsq,
                      float* __restrict__ marg, float* __restrict__ minv) {
    int gid = blockIdx.x * 256 + threadIdx.x;   // 32768
    int P = gid >> 1, half = gid & 1;
    const float* row = zT + (size_t)P * 256 + half * 128;
    float r[8];
    float S = 0.f;
    #pragma unroll
    for (int j = 0; j < 8; ++j) {
        float v = row[j];
        r[j] = mul_rn(v, v);
        S += fabsf(v);
    }
    for (int i = 8; i < 128; i += 8)
        #pragma unroll
        for (int j = 0; j < 8; ++j) {
            float v = row[i + j];
            r[j] += mul_rn(v, v);
            S += fabsf(v);
        }
    float s = ((r[0] + r[1]) + (r[2] + r[3])) + ((r[4] + r[5]) + (r[6] + r[7]));
    float so = __shfl_xor(s, 1, 64);
    float So = __shfl_xor(S, 1, 64);
    if (half == 0) {
        float zq = s + so;
        zsq[P] = zq;
        float Stot = S + So;
        unsigned int bits = __float_as_uint(zq);
        int ex = (int)((bits >> 23) & 255);
        float q = __uint_as_float((unsigned int)(ex - 23) << 23);  // ulp(zsq)
        float mg = 0.5f * q + 9.6e-7f * Stot + 2e-6f;
        marg[P] = mg;
        minv[P] = 32.0f / mg;
    }
}

// ---------------------------------------------------------------------------
// K_init: hist=0, pbest=+inf keys, counters = 0
// jc[0]=full jobs, jc[1]=single jobs, jc[2]=side count, jc[3]=side ovf flag
// ---------------------------------------------------------------------------
__global__ void k_init(int* __restrict__ hist,
                       unsigned long long* __restrict__ pbest,
                       int* __restrict__ jc) {
    int i = blockIdx.x * 256 + threadIdx.x;   // 16384
    if (i < NE) hist[i] = 0;
    pbest[i] = ~0ULL;
    if (i < 4) jc[i] = 0;
}

// ---------------------------------------------------------------------------
// K_gemm_f: single fused pass, 128x128 tile (validated geometry), XOR-swizzled
// LDS (validated), single barrier per K-iter, slim guarded emission:
// hits (g >= tileMax - marg) -> 4 bounded slots per (row,tile); overflow ->
// block-aggregated global side list. The hit SET {slots U side} is
// deterministic (placement isn't, but downstream treats both identically).
// ---------------------------------------------------------------------------
__global__ __launch_bounds__(256)
void k_gemm_f(const unsigned short* __restrict__ zhT,
              const unsigned short* __restrict__ eh,
              const float* __restrict__ marg,
              const float* __restrict__ minv,
              float* __restrict__ tileMax,
              unsigned short* __restrict__ slots,
              unsigned char* __restrict__ cnt,
              unsigned int* __restrict__ side, int* __restrict__ jc) {
    const int bid = blockIdx.x;
    const int bm = bid & 127;          // 128 point-tiles
    const int bn = bid >> 7;           // 64 code-tiles of 128
    const int t = threadIdx.x;
    const int l = t & 63, w = t >> 6, wm = w >> 1, wn = w & 1;

    __shared__ unsigned short As[2][128 * 32];
    __shared__ unsigned short Bs[2][128 * 32];
    __shared__ float wred[2][128];
    __shared__ float smarg[128];
    __shared__ float sminvl[128];
    __shared__ float staul[128];
    __shared__ int rowcnt[128];
    __shared__ unsigned int sbuf[SBUF];
    __shared__ int scnt, sgb;

    const unsigned short* Ab = zhT + (size_t)(bm * 128) * 256;
    const unsigned short* Bb = eh + (size_t)(bn * 128) * 256;
    const int srow = t >> 2;
    // swizzled source k-offset (shorts); dest stays linear t*16B (T2/m173)
    const int sk = ((t & 3) * 8) ^ (((t >> 3) & 3) << 3);

    gl_lds16(Ab + (size_t)srow * 256 + sk,        &As[0][t * 8]);
    gl_lds16(Ab + (size_t)(srow + 64) * 256 + sk, &As[0][t * 8 + 2048]);
    gl_lds16(Bb + (size_t)srow * 256 + sk,        &Bs[0][t * 8]);
    gl_lds16(Bb + (size_t)(srow + 64) * 256 + sk, &Bs[0][t * 8 + 2048]);

    if (t < 128) { smarg[t] = marg[bm * 128 + t]; sminvl[t] = minv[bm * 128 + t]; }
    if (t == 0) scnt = 0;

    f32x4 acc[4][4];
    #pragma unroll
    for (int m = 0; m < 4; ++m)
        #pragma unroll
        for (int n = 0; n < 4; ++n)
            acc[m][n] = (f32x4){0.f, 0.f, 0.f, 0.f};

    const int lx = l & 15;
    const int koS = ((l >> 4) * 8) ^ (((lx >> 1) & 3) << 3);
    const int r0 = wm * 64 + lx;
    const int c0 = wn * 64 + lx;

    __syncthreads();   // prologue stage drained
    int buf = 0;
    for (int kc = 0; kc < 8; ++kc) {
        if (kc < 7) {
            int kk = (kc + 1) * 32;
            gl_lds16(Ab + (size_t)srow * 256 + kk + sk,        &As[buf ^ 1][t * 8]);
            gl_lds16(Ab + (size_t)(srow + 64) * 256 + kk + sk, &As[buf ^ 1][t * 8 + 2048]);
            gl_lds16(Bb + (size_t)srow * 256 + kk + sk,        &Bs[buf ^ 1][t * 8]);
            gl_lds16(Bb + (size_t)(srow + 64) * 256 + kk + sk, &Bs[buf ^ 1][t * 8 + 2048]);
        }
        s16x8 af[4], bfr[4];
        #pragma unroll
        for (int m = 0; m < 4; ++m)
            af[m] = *(const s16x8*)&As[buf][(r0 + m * 16) * 32 + koS];
        #pragma unroll
        for (int n = 0; n < 4; ++n)
            bfr[n] = *(const s16x8*)&Bs[buf][(c0 + n * 16) * 32 + koS];
        #pragma unroll
        for (int m = 0; m < 4; ++m)
            #pragma unroll
            for (int n = 0; n < 4; ++n)
                acc[m][n] = __builtin_amdgcn_mfma_f32_16x16x32_bf16(
                    af[m], bfr[n], acc[m][n], 0, 0, 0);
        if (kc < 7) __syncthreads();  // drains next-tile stage + guards restage
        buf ^= 1;
    }

    // ---- epilogue: per-row tile max (keep per-thread pmax for the guard) ----
    float pmax[4][4];
    #pragma unroll
    for (int m = 0; m < 4; ++m)
        #pragma unroll
        for (int q = 0; q < 4; ++q) {
            float v = acc[m][0][q];
            v = fmaxf(v, acc[m][1][q]);
            v = fmaxf(v, acc[m][2][q]);
            v = fmaxf(v, acc[m][3][q]);
            pmax[m][q] = v;
        }
    #pragma unroll
    for (int m = 0; m < 4; ++m)
        #pragma unroll
        for (int q = 0; q < 4; ++q) {
            float v = pmax[m][q];
            #pragma unroll
            for (int msk = 1; msk < 16; msk <<= 1)
                v = fmaxf(v, __shfl_xor(v, msk, 64));
            if (lx == 0)
                wred[wn][wm * 64 + m * 16 + (l >> 4) * 4 + q] = v;
        }
    __syncthreads();
    if (t < 128) {
        float tm = fmaxf(wred[0][t], wred[1][t]);
        tileMax[(size_t)(bm * 128 + t) * NT + bn] = tm;
        staul[t] = tm - smarg[t];   // local tau (bitwise reproduced in k_filter)
        rowcnt[t] = 0;
    }
    __syncthreads();

    // ---- guarded emission ----
    #pragma unroll
    for (int m = 0; m < 4; ++m)
        #pragma unroll
        for (int q = 0; q < 4; ++q) {
            int row = wm * 64 + m * 16 + (l >> 4) * 4 + q;
            float st = staul[row];
            if (pmax[m][q] >= st) {
                float si = sminvl[row];
                unsigned int u = (unsigned int)((bm * 128 + row) * NT + bn);
                #pragma unroll
                for (int n = 0; n < 4; ++n) {
                    float g = acc[m][n][q];
                    if (g >= st) {
                        int eq = (int)((g - st) * si);
                        eq = eq < 0 ? 0 : (eq > 31 ? 31 : eq);
                        int cT = wn * 64 + n * 16 + lx;   // 0..127
                        int slot = atomicAdd(&rowcnt[row], 1);
                        if (slot < KSLOT) {
                            slots[(size_t)u * KSLOT + slot] =
                                (unsigned short)((eq << 8) | cT);
                        } else {
                            int sp = atomicAdd(&scnt, 1);
                            if (sp < SBUF)
                                sbuf[sp] = (u << 12) | ((unsigned int)eq << 7) |
                                           (unsigned int)cT;
                        }
                    }
                }
            }
        }
    __syncthreads();
    if (t < 128) {
        int c = rowcnt[t];
        cnt[(size_t)(bm * 128 + t) * NT + bn] = (unsigned char)(c > 255 ? 255 : c);
    }
    // ---- side-list block flush ----
    int ns = scnt;
    int nw = ns > SBUF ? SBUF : ns;
    if (t == 0) {
        if (ns > SBUF) atomicAdd(jc + 3, 1);          // poison flag (fallback)
        sgb = (nw > 0) ? atomicAdd(jc + 2, nw) : 0;
    }
    __syncthreads();
    int b0 = sgb;
    for (int i = t; i < nw; i += 256) {
        int pos = b0 + i;
        if (pos < OCAP) side[pos] = sbuf[i];
    }
}

// ---------------------------------------------------------------------------
// K_flag: tau[p] = max_T tileMax[p][T] - marg[p]  (global tau)
// ---------------------------------------------------------------------------
__global__ void k_flag(const float* __restrict__ tileMax,
                       const float* __restrict__ marg,
                       float* __restrict__ tau) {
    int p = blockIdx.x * 256 + threadIdx.x;
    const float* row = tileMax + (size_t)p * NT;
    float best = -1e30f;
    for (int T = 0; T < NT; T += 4) {
        float4 v = *(const float4*)(row + T);
        best = fmaxf(best, fmaxf(fmaxf(v.x, v.y), fmaxf(v.z, v.w)));
    }
    tau[p] = best - marg[p];
}

// ---------------------------------------------------------------------------
// K_filter: phase 1 = one thread per (p,T) unit (slot hits -> singles;
// in FALLBACK mode, cnt>KSLOT & tm>=tau -> full-tile job).
// phase 2 (normal mode) = grid-stride over side entries -> singles.
// Coverage proof: a code can win only if g >= tau; g <= tm, so tm>=tau gates
// full tiles; lb2 > g for stored hits, so lb2>tau keeps all winners.
// single job u32 = p<<13 | c.
// ---------------------------------------------------------------------------
__global__ void k_filter(const float* __restrict__ tileMax,
                         const float* __restrict__ marg,
                         const float* __restrict__ tau,
                         const unsigned short* __restrict__ slots,
                         const unsigned char* __restrict__ cnt,
                         const unsigned int* __restrict__ side,
                         int* __restrict__ jc,
                         unsigned int* __restrict__ jobs_full,
                         unsigned int* __restrict__ jobs_single) {
    int u = blockIdx.x * 256 + threadIdx.x;   // == NUNITS threads
    int nO = jc[2];
    bool fallback = (nO > OCAP) || (jc[3] > 0);

    {
        int p = u >> 6;
        int cv = cnt[u];
        float tm = tileMax[u];
        float tauv = tau[p];
        if (fallback && cv > KSLOT) {
            if (tm >= tauv) {
                int pos = atomicAdd(jc, 1);
                if (pos < FJCAP) jobs_full[pos] = (unsigned int)u;
            }
        }
        int ns = cv > KSLOT ? KSLOT : cv;
        float mg = marg[p];
        float stauL = tm - mg;              // bitwise == emission's local tau
        for (int s = 0; s < ns; ++s) {
            unsigned short sv = slots[(size_t)u * KSLOT + s];
            int eq = sv >> 8;
            float lb2 = stauL + (float)(eq + 2) * mg * 0.03125f;  // lb2 > g
            if (lb2 > tauv) {
                int c = (u & 63) * 128 + (sv & 127);
                int pos = atomicAdd(jc + 1, 1);
                if (pos < SJCAP)
                    jobs_single[pos] = ((unsigned int)p << 13) | (unsigned int)c;
            }
        }
    }

    if (!fallback) {
        int nS = nO > OCAP ? OCAP : nO;
        int stride = gridDim.x * 256;
        for (int j = u; j < nS; j += stride) {
            unsigned int e = side[j];
            unsigned int uu = e >> 12;
            int p = (int)(uu >> 6);
            int eq = (int)((e >> 7) & 31u);
            float mg = marg[p];
            float lb2 = (tileMax[uu] - mg) + (float)(eq + 2) * mg * 0.03125f;
            if (lb2 > tau[p]) {
                int c = (int)(uu & 63u) * 128 + (int)(e & 127u);
                int pos = atomicAdd(jc + 1, 1);
                if (pos < SJCAP)
                    jobs_single[pos] = ((unsigned int)p << 13) | (unsigned int)c;
            }
        }
    }
}

// ---------------------------------------------------------------------------
// K_rescore: lane-parallel singles; wave-parallel full tiles (fallback only).
// ---------------------------------------------------------------------------
__global__ __launch_bounds__(256)
void k_rescore(const unsigned int* __restrict__ jobs_full,
               const unsigned int* __restrict__ jobs_single,
               const int* __restrict__ jc,
               const float* __restrict__ zT, const float* __restrict__ e,
               const float* __restrict__ zsq,
               unsigned long long* __restrict__ pbest) {
    int tid = blockIdx.x * 256 + threadIdx.x;
    int stride = gridDim.x * 256;

    int nS = jc[1]; if (nS > SJCAP) nS = SJCAP;
    for (int j = tid; j < nS; j += stride) {
        unsigned int v = jobs_single[j];
        int p = (int)(v >> 13);
        int c = (int)(v & 8191u);
        dot_min(zT + (size_t)p * 256, e, zsq[p], p, c, pbest);
    }

    int nF = jc[0]; if (nF > FJCAP) nF = FJCAP;
    int wid = tid >> 6, lane = threadIdx.x & 63, nw = stride >> 6;
    for (int j = wid; j < nF; j += nw) {
        int u = (int)(jobs_full[j] & 0xFFFFFu);
        int p = u >> 6, T = u & 63;
        const float* zp = zT + (size_t)p * 256;
        float zq = zsq[p];
        for (int r = lane; r < 128; r += 64)
            dot_min(zp, e, zq, p, T * 128 + r, pbest);
    }
}

// ---------------------------------------------------------------------------
// K_pick: unpack pbest -> idx + histogram
// ---------------------------------------------------------------------------
__global__ void k_pick(const unsigned long long* __restrict__ pbest,
                       int* __restrict__ idx_i, int* __restrict__ hist,
                       float* __restrict__ out) {
    int P = blockIdx.x * 256 + threadIdx.x;
    unsigned long long key = pbest[P];
    int idx = (int)(unsigned int)(key & 0xffffffffULL);
    idx_i[P] = idx;
    out[OFF_IDX + P] = (float)idx;
    atomicAdd(&hist[idx], 1);
}

// ---------------------------------------------------------------------------
// K_gather: z_q NCHW with STE rounding fl(z + fl(e - z)), loss partials
// ---------------------------------------------------------------------------
__global__ __launch_bounds__(256)
void k_gather(const float* __restrict__ z, const float* __restrict__ emb,
              const int* __restrict__ idx_i, float* __restrict__ out,
              float* __restrict__ partials) {
    int bid = blockIdx.x;          // 0..4095
    int c = bid & 255;
    int b = bid >> 8;
    int t = threadIdx.x;
    int hw = t * 4;

    size_t zoff = (size_t)(b * DIM + c) * HW + hw;
    const float4 zv = *(const float4*)(z + zoff);
    const int4  iv = *(const int4*)(idx_i + b * HW + hw);

    float e0 = emb[(size_t)iv.x * DIM + c];
    float e1 = emb[(size_t)iv.y * DIM + c];
    float e2 = emb[(size_t)iv.z * DIM + c];
    float e3 = emb[(size_t)iv.w * DIM + c];

    float dx = e0 - zv.x, dy = e1 - zv.y, dz = e2 - zv.z, dw = e3 - zv.w;
    float4 ov = make_float4(zv.x + dx, zv.y + dy, zv.z + dz, zv.w + dw);
    *(float4*)(out + zoff) = ov;

    float sq = dx * dx + dy * dy + dz * dz + dw * dw;
    #pragma unroll
    for (int m = 32; m >= 1; m >>= 1) sq += __shfl_xor(sq, m, 64);
    __shared__ float red[4];
    if ((t & 63) == 0) red[t >> 6] = sq;
    __syncthreads();
    if (t == 0) partials[bid] = red[0] + red[1] + red[2] + red[3];
}

// ---------------------------------------------------------------------------
// K_final: loss + perplexity (f64)
// ---------------------------------------------------------------------------
__global__ void k_final(const float* __restrict__ partials,
                        const int* __restrict__ hist,
                        float* __restrict__ out) {
    int t = threadIdx.x;
    double ls = 0.0, es = 0.0;
    for (int i = t; i < 4096; i += 256) ls += (double)partials[i];
    for (int i = t; i < NE; i += 256) {
        double em = (double)hist[i] / (double)NPTS;
        es += em * log(em + 1e-10);
    }
    __shared__ double s1[256], s2[256];
    s1[t] = ls; s2[t] = es;
    __syncthreads();
    for (int s = 128; s > 0; s >>= 1) {
        if (t < s) { s1[t] += s1[t + s]; s2[t] += s2[t + s]; }
        __syncthreads();
    }
    if (t == 0) {
        out[OFF_LOSS] = (float)(s1[0] / (double)ZQ_N * 1.25);
        out[OFF_PERP] = (float)exp(-s2[0]);
    }
}

// ===========================================================================
// Fallback path (validated round-2 brute force) — used if ws_size too small
// ===========================================================================
__global__ void f_zsq(const float* __restrict__ z, float* __restrict__ zsq) {
    int gid = blockIdx.x * 256 + threadIdx.x;
    int P = gid >> 1, half = gid & 1;
    int b = P >> 10, hw = P & 1023;
    const float* zb = z + (size_t)b * (DIM * HW) + (size_t)(half * 128) * HW + hw;
    float r[8];
    #pragma unroll
    for (int j = 0; j < 8; ++j) {
        float v = zb[(size_t)j * HW];
        r[j] = mul_rn(v, v);
    }
    #pragma unroll
    for (int i = 8; i < 128; i += 8)
        #pragma unroll
        for (int j = 0; j < 8; ++j) {
            float v = zb[(size_t)(i + j) * HW];
            r[j] += mul_rn(v, v);
        }
    float s = ((r[0] + r[1]) + (r[2] + r[3])) + ((r[4] + r[5]) + (r[6] + r[7]));
    float o = __shfl_xor(s, 1, 64);
    if (half == 0) zsq[P] = s + o;
}

__global__ void f_init(int* __restrict__ hist) {
    hist[blockIdx.x * 256 + threadIdx.x] = 0;
}

#define FBP 64
#define FBC 256
#define FKC 32
__global__ __launch_bounds__(256, 2)
void f_argmin(const float* __restrict__ z, const float* __restrict__ emb,
              const float* __restrict__ zsq,
              float* __restrict__ cand_d, int* __restrict__ cand_c) {
    const int blk = blockIdx.x;
    const int pblk = blk & 255;
    const int split = blk >> 8;
    const int p0 = pblk * FBP;
    const int b = p0 >> 10;
    const int hw0 = p0 & 1023;
    const int t = threadIdx.x;
    const int tx = t & 31;
    const int ty = t >> 5;

    __shared__ __align__(16) float z_s[FBP][36];
    __shared__ __align__(16) float e_s[FBC][36];

    float bd[8];
    int bcn[8];
    #pragma unroll
    for (int i = 0; i < 8; ++i) { bd[i] = INFINITY; bcn[i] = 0x7fffffff; }
    float zsqv[8];
    #pragma unroll
    for (int i = 0; i < 8; ++i) zsqv[i] = zsq[p0 + ty * 8 + i];

    const float* zbase = z + (size_t)b * (DIM * HW) + hw0;

    for (int cc = split * 16; cc < (split + 1) * 16; ++cc) {
        float acc[8][8];
        #pragma unroll
        for (int i = 0; i < 8; ++i)
            #pragma unroll
            for (int j = 0; j < 8; ++j) acc[i][j] = 0.f;
        for (int kc = 0; kc < DIM / FKC; ++kc) {
            __syncthreads();
            {
                int i = t & 63, kk0 = t >> 6;
                #pragma unroll
                for (int r = 0; r < 8; ++r) {
                    int kk = kk0 + r * 4;
                    z_s[i][kk] = zbase[(size_t)(kc * FKC + kk) * HW + i];
                }
            }
            {
                #pragma unroll
                for (int it = 0; it < 8; ++it) {
                    int q = t + it * 256;
                    int r = q >> 3, kkq = q & 7;
                    const float4 v = *(const float4*)(emb +
                        (size_t)(cc * FBC + r) * DIM + kc * FKC + kkq * 4);
                    *(float4*)&e_s[r][kkq * 4] = v;
                }
            }
            __syncthreads();
            #pragma unroll
            for (int g = 0; g < 8; ++g) {
                float4 zf[8], ef[8];
                #pragma unroll
                for (int i = 0; i < 8; ++i)
                    zf[i] = *(const float4*)&z_s[ty * 8 + i][g * 4];
                #pragma unroll
                for (int j = 0; j < 8; ++j)
                    ef[j] = *(const float4*)&e_s[tx + j * 32][g * 4];
                #pragma unroll
                for (int i = 0; i < 8; ++i)
                    #pragma unroll
                    for (int j = 0; j < 8; ++j) {
                        float a = acc[i][j];
                        a = fmaf(zf[i].x, ef[j].x, a);
                        a = fmaf(zf[i].y, ef[j].y, a);
                        a = fmaf(zf[i].z, ef[j].z, a);
                        a = fmaf(zf[i].w, ef[j].w, a);
                        acc[i][j] = a;
                    }
            }
        }
        #pragma unroll
        for (int j = 0; j < 8; ++j) {
            int c = cc * FBC + tx + j * 32;
            #pragma unroll
            for (int i = 0; i < 8; ++i) {
                float d = zsqv[i] - 2.0f * acc[i][j];
                if (d < bd[i]) { bd[i] = d; bcn[i] = c; }
                else if (d == bd[i] && c < bcn[i]) { bcn[i] = c; }
            }
        }
    }
    #pragma unroll
    for (int i = 0; i < 8; ++i) {
        float d = bd[i];
        int c = bcn[i];
        #pragma unroll
        for (int m = 16; m >= 1; m >>= 1) {
            float od = __shfl_xor(d, m, 32);
            int oc = __shfl_xor(c, m, 32);
            if (od < d || (od == d && oc < c)) { d = od; c = oc; }
        }
        if (tx == 0) {
            int P = p0 + ty * 8 + i;
            cand_d[(size_t)split * NPTS + P] = d;
            cand_c[(size_t)split * NPTS + P] = c;
        }
    }
}

__global__ void f_pick(const float* __restrict__ cand_d,
                       const int* __restrict__ cand_c,
                       int* __restrict__ idx_i, int* __restrict__ hist,
                       float* __restrict__ out) {
    int P = blockIdx.x * 256 + threadIdx.x;
    float d0 = cand_d[P], d1 = cand_d[NPTS + P];
    int c0 = cand_c[P], c1 = cand_c[NPTS + P];
    int idx = (d1 < d0) ? c1 : c0;
    idx_i[P] = idx;
    out[OFF_IDX + P] = (float)idx;
    atomicAdd(&hist[idx], 1);
}

// ---------------------------------------------------------------------------
extern "C" void kernel_launch(void* const* d_in, const int* in_sizes, int n_in,
                              void* d_out, int out_size, void* d_ws, size_t ws_size,
                              hipStream_t stream) {
    const float* z   = (const float*)d_in[0];   // [16,256,32,32]
    const float* emb = (const float*)d_in[1];   // [8192,256]
    float* out = (float*)d_out;
    char*  ws  = (char*)d_ws;

    // ---- main-path ws layout (bytes), NEED = 29,322,560 ----
    const size_t O_ZHT  = 0;             // 8,388,608  (jobs_single after gemm)
    const size_t O_EH   = 8388608;       // 4,194,304  (jobs_full after gemm)
    const size_t O_TM   = 12582912;      // 4,194,304  tileMax f32 [NPTS][NT]
    const size_t O_SLOT = 16777216;      // 8,388,608  u16 [NPTS][NT][KSLOT]
    const size_t O_CNT  = 25165824;      // 1,048,576  u8  [NPTS][NT]
    const size_t O_ZSQ  = 26214400;      //    65,536
    const size_t O_MARG = 26279936;      //    65,536
    const size_t O_MINV = 26345472;      //    65,536
    const size_t O_TAU  = 26411008;      //    65,536
    const size_t O_PB   = 26476544;      //   131,072
    const size_t O_IDX  = 26607616;      //    65,536
    const size_t O_HIST = 26673152;      //    32,768
    const size_t O_PART = 26705920;      //    16,384
    const size_t O_JC   = 26722304;      //       256
    const size_t O_SIDE = 26722560;      // 2,600,000  u32 side list (OCAP)
    const size_t NEED   = O_SIDE + (size_t)OCAP * 4;

    if (ws_size >= NEED) {
        float* zT = out;   // f32 [16384][256] in z_q region; overwritten by k_gather
        unsigned short* zhT   = (unsigned short*)(ws + O_ZHT);
        unsigned short* eh    = (unsigned short*)(ws + O_EH);
        float* tileMax        = (float*)(ws + O_TM);
        unsigned short* slots = (unsigned short*)(ws + O_SLOT);
        unsigned char* cnt    = (unsigned char*)(ws + O_CNT);
        float* zsq            = (float*)(ws + O_ZSQ);
        float* marg           = (float*)(ws + O_MARG);
        float* minv           = (float*)(ws + O_MINV);
        float* tau            = (float*)(ws + O_TAU);
        unsigned long long* pbest = (unsigned long long*)(ws + O_PB);
        int*   idx_i          = (int*)(ws + O_IDX);
        int*   hist           = (int*)(ws + O_HIST);
        float* partials       = (float*)(ws + O_PART);
        int*   jc             = (int*)(ws + O_JC);
        unsigned int* side    = (unsigned int*)(ws + O_SIDE);
        // job lists alias the (dead after k_gemm_f) zhT/eh regions
        unsigned int* jobs_single = (unsigned int*)(ws + O_ZHT);  // SJCAP u32
        unsigned int* jobs_full   = (unsigned int*)(ws + O_EH);   // FJCAP u32

        k_prep_z <<<1024, 256, 0, stream>>>(z, zT, zhT);
        k_prep_e <<<512,  256, 0, stream>>>(emb, eh);
        k_zsq    <<<128,  256, 0, stream>>>(zT, zsq, marg, minv);
        k_init   <<<64,   256, 0, stream>>>(hist, pbest, jc);
        k_gemm_f <<<8192, 256, 0, stream>>>(zhT, eh, marg, minv, tileMax,
                                            slots, cnt, side, jc);
        k_flag   <<<64,   256, 0, stream>>>(tileMax, marg, tau);
        k_filter <<<4096, 256, 0, stream>>>(tileMax, marg, tau, slots, cnt,
                                            side, jc, jobs_full, jobs_single);
        k_rescore<<<1024, 256, 0, stream>>>(jobs_full, jobs_single, jc,
                                            zT, emb, zsq, pbest);
        k_pick   <<<64,   256, 0, stream>>>(pbest, idx_i, hist, out);
        k_gather <<<4096, 256, 0, stream>>>(z, emb, idx_i, out, partials);
        k_final  <<<1,    256, 0, stream>>>(partials, hist, out);
    } else {
        // fallback: validated round-2 brute-force path (~442KB ws)
        float* zsq      = (float*)(ws);
        int*   hist     = (int*)  (ws + 65536);
        float* cand_d   = (float*)(ws + 98304);
        int*   cand_c   = (int*)  (ws + 229376);
        int*   idx_i    = (int*)  (ws + 360448);
        float* partials = (float*)(ws + 425984);

        f_zsq   <<<128, 256, 0, stream>>>(z, zsq);
        f_init  <<<32, 256, 0, stream>>>(hist);
        f_argmin<<<512, 256, 0, stream>>>(z, emb, zsq, cand_d, cand_c);
        f_pick  <<<64, 256, 0, stream>>>(cand_d, cand_c, idx_i, hist, out);
        k_gather<<<4096, 256, 0, stream>>>(z, emb, idx_i, out, partials);
        k_final <<<1, 256, 0, stream>>>(partials, hist, out);
    }
}

// Round 9
// 479.548 us; speedup vs baseline: 1.1036x; 1.1036x over previous
//
#include <hip/hip_runtime.h>
#include <math.h>

// Problem constants
#define NPTS   16384      // 16*32*32 points
#define NE     8192       // codebook entries
#define DIM    256        // embedding dim
#define BIMG   16
#define HW     1024       // 32*32
#define ZQ_N   4194304
#define OFF_LOSS  4194304
#define OFF_PERP  4194305
#define OFF_IDX   4194306

#define NT     64                   // code tiles of 128 (= GEMM BN)
#define NUNITS (NPTS * NT)          // 1,048,576 (p,T) units

typedef short s16x8 __attribute__((ext_vector_type(8)));
typedef float f32x4 __attribute__((ext_vector_type(4)));

// f32 multiply that can NOT be contracted into an FMA (numpy rounds zf*zf).
__device__ __forceinline__ float mul_rn(float a, float b) {
    float r;
    asm("v_mul_f32 %0, %1, %2" : "=v"(r) : "v"(a), "v"(b));
    return r;
}

// RNE float -> bf16 bits
__device__ __forceinline__ unsigned short f2bf(float f) {
    unsigned int u = __float_as_uint(f);
    return (unsigned short)((u + 0x7fffu + ((u >> 16) & 1u)) >> 16);
}

// monotone f32 -> u32 order-preserving bits, and inverse (exact bijection)
__device__ __forceinline__ unsigned int f2ord(float f) {
    unsigned int b = __float_as_uint(f);
    return (b & 0x80000000u) ? ~b : (b ^ 0x80000000u);
}
__device__ __forceinline__ float ord2f(unsigned int o) {
    unsigned int b = (o & 0x80000000u) ? (o ^ 0x80000000u) : ~o;
    return __uint_as_float(b);
}

__device__ __forceinline__ void gl_lds16(const void* g, void* l) {
    __builtin_amdgcn_global_load_lds(
        (const __attribute__((address_space(1))) void*)g,
        (__attribute__((address_space(3))) void*)l, 16, 0, 0);
}

// exact f32 chain dot (bit-identical to validated reference semantics) + min
__device__ __forceinline__ void dot_min(const float* __restrict__ zp,
                                        const float* __restrict__ e,
                                        float zq, int p, int c,
                                        unsigned long long* __restrict__ pbest) {
    const float4* zp4 = (const float4*)zp;
    const float4* ep = (const float4*)(e + (size_t)c * 256);
    float a = 0.f;
    for (int k4 = 0; k4 < 64; ++k4) {
        float4 zv = zp4[k4];
        float4 ev = ep[k4];
        a = fmaf(zv.x, ev.x, a);   // k ascending, single accumulator,
        a = fmaf(zv.y, ev.y, a);   // fused per step (validated round 2)
        a = fmaf(zv.z, ev.z, a);
        a = fmaf(zv.w, ev.w, a);
    }
    float d = zq - 2.0f * a;
    unsigned long long key =
        ((unsigned long long)__float_as_uint(d) << 32) | (unsigned int)c;
    atomicMin(pbest + p, key);
}

// ---------------------------------------------------------------------------
// K_prep_z: z[b][k][hw] -> zT[p][k] f32 (into d_out z_q region) + zhT bf16
// ---------------------------------------------------------------------------
__global__ __launch_bounds__(256)
void k_prep_z(const float* __restrict__ z, float* __restrict__ zT,
              unsigned short* __restrict__ zhT) {
    int bid = blockIdx.x;
    int ht = bid & 15, kt = (bid >> 4) & 3, b = bid >> 6;
    int k0 = kt * 64, hw0 = ht * 64;
    __shared__ float lt[64][65];
    int t = threadIdx.x;
    {
        int kr = t >> 2, j4 = (t & 3) * 16;
        const float* src = z + ((size_t)b * 256 + k0 + kr) * 1024 + hw0 + j4;
        #pragma unroll
        for (int q = 0; q < 4; ++q) {
            float4 v = *(const float4*)(src + q * 4);
            lt[kr][j4 + q * 4 + 0] = v.x; lt[kr][j4 + q * 4 + 1] = v.y;
            lt[kr][j4 + q * 4 + 2] = v.z; lt[kr][j4 + q * 4 + 3] = v.w;
        }
    }
    __syncthreads();
    {
        int pr = t >> 2, kb = (t & 3) * 16;
        size_t p = (size_t)b * 1024 + hw0 + pr;
        float vals[16];
        #pragma unroll
        for (int i = 0; i < 16; ++i) vals[i] = lt[kb + i][pr];
        float* dst = zT + p * 256 + k0 + kb;
        #pragma unroll
        for (int q = 0; q < 4; ++q)
            *(float4*)(dst + q * 4) = make_float4(vals[q*4], vals[q*4+1],
                                                  vals[q*4+2], vals[q*4+3]);
        unsigned short* hd = zhT + p * 256 + k0 + kb;
        #pragma unroll
        for (int q = 0; q < 4; ++q) {
            ushort4 h;
            h.x = f2bf(vals[q*4]);   h.y = f2bf(vals[q*4+1]);
            h.z = f2bf(vals[q*4+2]); h.w = f2bf(vals[q*4+3]);
            *(ushort4*)(hd + q * 4) = h;
        }
    }
}

// ---------------------------------------------------------------------------
// K_prep_e: e[c][k] f32 -> eh bf16
// ---------------------------------------------------------------------------
__global__ void k_prep_e(const float* __restrict__ e, unsigned short* __restrict__ eh) {
    size_t i = ((size_t)blockIdx.x * 256 + threadIdx.x) * 16;
    #pragma unroll
    for (int q = 0; q < 4; ++q) {
        float4 v = *(const float4*)(e + i + q * 4);
        ushort4 h;
        h.x = f2bf(v.x); h.y = f2bf(v.y); h.z = f2bf(v.z); h.w = f2bf(v.w);
        *(ushort4*)(eh + i + q * 4) = h;
    }
}

// ---------------------------------------------------------------------------
// K_zsq: numpy-pairwise ||z||^2 (validated) + sound margin
// ---------------------------------------------------------------------------
__global__ void k_zsq(const float* __restrict__ zT, float* __restrict__ zsq,
                      float* __restrict__ marg) {
    int gid = blockIdx.x * 256 + threadIdx.x;   // 32768
    int P = gid >> 1, half = gid & 1;
    const float* row = zT + (size_t)P * 256 + half * 128;
    float r[8];
    float S = 0.f;
    #pragma unroll
    for (int j = 0; j < 8; ++j) {
        float v = row[j];
        r[j] = mul_rn(v, v);
        S += fabsf(v);
    }
    for (int i = 8; i < 128; i += 8)
        #pragma unroll
        for (int j = 0; j < 8; ++j) {
            float v = row[i + j];
            r[j] += mul_rn(v, v);
            S += fabsf(v);
        }
    float s = ((r[0] + r[1]) + (r[2] + r[3])) + ((r[4] + r[5]) + (r[6] + r[7]));
    float so = __shfl_xor(s, 1, 64);
    float So = __shfl_xor(S, 1, 64);
    if (half == 0) {
        float zq = s + so;
        zsq[P] = zq;
        float Stot = S + So;
        unsigned int bits = __float_as_uint(zq);
        int ex = (int)((bits >> 23) & 255);
        float q = __uint_as_float((unsigned int)(ex - 23) << 23);  // ulp(zsq)
        marg[P] = 0.5f * q + 9.6e-7f * Stot + 2e-6f;
    }
}

// ---------------------------------------------------------------------------
// K_init: hist=0, pbest=+inf keys, job counters = 0
// ---------------------------------------------------------------------------
__global__ void k_init(int* __restrict__ hist,
                       unsigned long long* __restrict__ pbest,
                       int* __restrict__ jc) {
    int i = blockIdx.x * 256 + threadIdx.x;   // 16384
    if (i < NE) hist[i] = 0;
    pbest[i] = ~0ULL;
    if (i < 2) jc[i] = 0;
}

// ---------------------------------------------------------------------------
// K_gemm_f: ONE pass, 128x128 tile, round-4's measured two-barrier K-loop +
// swizzled LDS. Epilogue computes per (point,tile) a pure-register summary:
//   tm  = max_c g, c1 = argmax col (lowest col, deterministic),
//   cnt = #{c : g >= tm - marg}  (saturated at 63)
// packed u64 = ord(tm)<<32 | cnt<<7 | c1, stored [T][p]-coalesced.
// No atomics, no lists -> fully deterministic by construction.
// ---------------------------------------------------------------------------
__global__ __launch_bounds__(256)
void k_gemm_f(const unsigned short* __restrict__ zhT,
              const unsigned short* __restrict__ eh,
              const float* __restrict__ marg,
              unsigned long long* __restrict__ tilinfo) {
    const int bid = blockIdx.x;
    const int bm = bid & 127;          // 128 point-tiles
    const int bn = bid >> 7;           // 64 code-tiles of 128
    const int t = threadIdx.x;
    const int l = t & 63, w = t >> 6, wm = w >> 1, wn = w & 1;

    __shared__ unsigned short As[2][128 * 32];
    __shared__ unsigned short Bs[2][128 * 32];
    __shared__ float        wredG[2][128];
    __shared__ unsigned int wredC[2][128];
    __shared__ unsigned int wredN[2][128];
    __shared__ float smarg[128];
    __shared__ float staul[128];

    const unsigned short* Ab = zhT + (size_t)(bm * 128) * 256;
    const unsigned short* Bb = eh + (size_t)(bn * 128) * 256;
    const int srow = t >> 2;
    // swizzled source k-offset (shorts); dest stays linear t*16B (T2/m173)
    const int sk = ((t & 3) * 8) ^ (((t >> 3) & 3) << 3);

    gl_lds16(Ab + (size_t)srow * 256 + sk,        &As[0][t * 8]);
    gl_lds16(Ab + (size_t)(srow + 64) * 256 + sk, &As[0][t * 8 + 2048]);
    gl_lds16(Bb + (size_t)srow * 256 + sk,        &Bs[0][t * 8]);
    gl_lds16(Bb + (size_t)(srow + 64) * 256 + sk, &Bs[0][t * 8 + 2048]);

    if (t < 128) smarg[t] = marg[bm * 128 + t];

    f32x4 acc[4][4];
    #pragma unroll
    for (int m = 0; m < 4; ++m)
        #pragma unroll
        for (int n = 0; n < 4; ++n)
            acc[m][n] = (f32x4){0.f, 0.f, 0.f, 0.f};

    const int lx = l & 15;
    const int koS = ((l >> 4) * 8) ^ (((lx >> 1) & 3) << 3);
    const int r0 = wm * 64 + lx;
    const int c0 = wn * 64 + lx;

    int buf = 0;
    for (int kc = 0; kc < 8; ++kc) {
        __syncthreads();   // staged data for this kc ready (vmcnt drained)
        if (kc < 7) {
            int kk = (kc + 1) * 32;
            gl_lds16(Ab + (size_t)srow * 256 + kk + sk,        &As[buf ^ 1][t * 8]);
            gl_lds16(Ab + (size_t)(srow + 64) * 256 + kk + sk, &As[buf ^ 1][t * 8 + 2048]);
            gl_lds16(Bb + (size_t)srow * 256 + kk + sk,        &Bs[buf ^ 1][t * 8]);
            gl_lds16(Bb + (size_t)(srow + 64) * 256 + kk + sk, &Bs[buf ^ 1][t * 8 + 2048]);
        }
        s16x8 af[4], bfr[4];
        #pragma unroll
        for (int m = 0; m < 4; ++m)
            af[m] = *(const s16x8*)&As[buf][(r0 + m * 16) * 32 + koS];
        #pragma unroll
        for (int n = 0; n < 4; ++n)
            bfr[n] = *(const s16x8*)&Bs[buf][(c0 + n * 16) * 32 + koS];
        #pragma unroll
        for (int m = 0; m < 4; ++m)
            #pragma unroll
            for (int n = 0; n < 4; ++n)
                acc[m][n] = __builtin_amdgcn_mfma_f32_16x16x32_bf16(
                    af[m], bfr[n], acc[m][n], 0, 0, 0);
        __syncthreads();   // all reads of buf done before it is restaged
        buf ^= 1;
    }

    // ---- epilogue phase A: per-row (max g, argmax col), deterministic ----
    #pragma unroll
    for (int m = 0; m < 4; ++m)
        #pragma unroll
        for (int q = 0; q < 4; ++q) {
            float g = acc[m][0][q];
            unsigned int c = (unsigned int)(c0);          // col of n=0
            #pragma unroll
            for (int n = 1; n < 4; ++n) {                  // ascending cols:
                float gn = acc[m][n][q];                   // strict > keeps
                unsigned int cn = (unsigned int)(c0 + n * 16);  // lowest col
                if (gn > g) { g = gn; c = cn; }
            }
            #pragma unroll
            for (int msk = 1; msk < 16; msk <<= 1) {
                float og = __shfl_xor(g, msk, 64);
                unsigned int oc = __shfl_xor(c, msk, 64);
                if (og > g || (og == g && oc < c)) { g = og; c = oc; }
            }
            if (lx == 0) {
                int row = wm * 64 + m * 16 + (l >> 4) * 4 + q;
                wredG[wn][row] = g;
                wredC[wn][row] = c;
            }
        }
    __syncthreads();
    if (t < 128) {
        float g0 = wredG[0][t], g1 = wredG[1][t];
        // warp0 cols (0..63) < warp1 cols: strict > keeps lower col on tie
        unsigned int c = (g1 > g0) ? wredC[1][t] : wredC[0][t];
        float tm = fmaxf(g0, g1);
        staul[t] = tm - smarg[t];
        wredG[0][t] = tm;     // stash for packing
        wredC[0][t] = c;
    }
    __syncthreads();

    // ---- epilogue phase B: count hits g >= tm - marg ----
    #pragma unroll
    for (int m = 0; m < 4; ++m)
        #pragma unroll
        for (int q = 0; q < 4; ++q) {
            int row = wm * 64 + m * 16 + (l >> 4) * 4 + q;
            float st = staul[row];
            int n4 = (acc[m][0][q] >= st) + (acc[m][1][q] >= st) +
                     (acc[m][2][q] >= st) + (acc[m][3][q] >= st);
            #pragma unroll
            for (int msk = 1; msk < 16; msk <<= 1)
                n4 += __shfl_xor(n4, msk, 64);
            if (lx == 0) wredN[wn][row] = (unsigned int)n4;
        }
    __syncthreads();
    if (t < 128) {
        unsigned int cnt = wredN[0][t] + wredN[1][t];
        if (cnt > 63u) cnt = 63u;
        unsigned long long ti =
            ((unsigned long long)f2ord(wredG[0][t]) << 32) |
            (cnt << 7) | (wredC[0][t] & 127u);
        tilinfo[(size_t)bn * NPTS + bm * 128 + t] = ti;   // [T][p] coalesced
    }
}

// ---------------------------------------------------------------------------
// K_flag: tau[p] = max_T tm - marg[p]   (ord-bits max, exact inverse)
// ---------------------------------------------------------------------------
__global__ void k_flag(const unsigned long long* __restrict__ tilinfo,
                       const float* __restrict__ marg,
                       float* __restrict__ tau) {
    int p = blockIdx.x * 256 + threadIdx.x;
    unsigned int mo = 0;
    for (int T = 0; T < NT; ++T) {
        unsigned int o = (unsigned int)(tilinfo[(size_t)T * NPTS + p] >> 32);
        mo = o > mo ? o : mo;
    }
    tau[p] = ord2f(mo) - marg[p];
}

// ---------------------------------------------------------------------------
// K_filter: one thread per (p,T) unit, at most ONE job per unit (structural
// capacity => no overflow, fully deterministic set). tm >= tau gates; then
// cnt<=1 -> single exact-dot job on the known argmax col; cnt>=2 -> full-tile.
// Soundness: codes other than c1 have g < tm - marg <= tau, so when cnt<=1
// no other code in the tile can be the argmin.
// ---------------------------------------------------------------------------
__global__ void k_filter(const unsigned long long* __restrict__ tilinfo,
                         const float* __restrict__ tau,
                         unsigned int* __restrict__ jobs_s,
                         unsigned int* __restrict__ jobs_f,
                         int* __restrict__ jc) {
    int u = blockIdx.x * 256 + threadIdx.x;   // u = T*NPTS + p
    unsigned long long ti = tilinfo[u];
    int p = u & (NPTS - 1);
    float tm = ord2f((unsigned int)(ti >> 32));
    if (tm >= tau[p]) {
        unsigned int cnt = ((unsigned int)ti >> 7) & 63u;
        if (cnt <= 1u) {
            int T = u >> 14;
            int c = T * 128 + (int)(ti & 127u);
            int pos = atomicAdd(jc, 1);
            if (pos < NUNITS) jobs_s[pos] = ((unsigned int)p << 13) | (unsigned int)c;
        } else {
            int pos = atomicAdd(jc + 1, 1);
            if (pos < NUNITS) jobs_f[pos] = (unsigned int)u;
        }
    }
}

// ---------------------------------------------------------------------------
// K_rescore: lane-parallel singles; wave-parallel full tiles.
// ---------------------------------------------------------------------------
__global__ __launch_bounds__(256)
void k_rescore(const unsigned int* __restrict__ jobs_s,
               const unsigned int* __restrict__ jobs_f,
               const int* __restrict__ jc,
               const float* __restrict__ zT, const float* __restrict__ e,
               const float* __restrict__ zsq,
               unsigned long long* __restrict__ pbest) {
    int tid = blockIdx.x * 256 + threadIdx.x;
    int stride = gridDim.x * 256;

    int nS = jc[0]; if (nS > NUNITS) nS = NUNITS;
    for (int j = tid; j < nS; j += stride) {
        unsigned int v = jobs_s[j];
        int p = (int)(v >> 13);
        int c = (int)(v & 8191u);
        dot_min(zT + (size_t)p * 256, e, zsq[p], p, c, pbest);
    }

    int nF = jc[1]; if (nF > NUNITS) nF = NUNITS;
    int wid = tid >> 6, lane = threadIdx.x & 63, nw = stride >> 6;
    for (int j = wid; j < nF; j += nw) {
        unsigned int u = jobs_f[j];
        int p = (int)(u & (NPTS - 1)), T = (int)(u >> 14);
        const float* zp = zT + (size_t)p * 256;
        float zq = zsq[p];
        for (int r = lane; r < 128; r += 64)
            dot_min(zp, e, zq, p, T * 128 + r, pbest);
    }
}

// ---------------------------------------------------------------------------
// K_pick: unpack pbest -> idx + histogram
// ---------------------------------------------------------------------------
__global__ void k_pick(const unsigned long long* __restrict__ pbest,
                       int* __restrict__ idx_i, int* __restrict__ hist,
                       float* __restrict__ out) {
    int P = blockIdx.x * 256 + threadIdx.x;
    unsigned long long key = pbest[P];
    int idx = (int)(unsigned int)(key & 0xffffffffULL);
    idx_i[P] = idx;
    out[OFF_IDX + P] = (float)idx;
    atomicAdd(&hist[idx], 1);
}

// ---------------------------------------------------------------------------
// K_gather: z_q NCHW with STE rounding fl(z + fl(e - z)), loss partials
// ---------------------------------------------------------------------------
__global__ __launch_bounds__(256)
void k_gather(const float* __restrict__ z, const float* __restrict__ emb,
              const int* __restrict__ idx_i, float* __restrict__ out,
              float* __restrict__ partials) {
    int bid = blockIdx.x;          // 0..4095
    int c = bid & 255;
    int b = bid >> 8;
    int t = threadIdx.x;
    int hw = t * 4;

    size_t zoff = (size_t)(b * DIM + c) * HW + hw;
    const float4 zv = *(const float4*)(z + zoff);
    const int4  iv = *(const int4*)(idx_i + b * HW + hw);

    float e0 = emb[(size_t)iv.x * DIM + c];
    float e1 = emb[(size_t)iv.y * DIM + c];
    float e2 = emb[(size_t)iv.z * DIM + c];
    float e3 = emb[(size_t)iv.w * DIM + c];

    float dx = e0 - zv.x, dy = e1 - zv.y, dz = e2 - zv.z, dw = e3 - zv.w;
    float4 ov = make_float4(zv.x + dx, zv.y + dy, zv.z + dz, zv.w + dw);
    *(float4*)(out + zoff) = ov;

    float sq = dx * dx + dy * dy + dz * dz + dw * dw;
    #pragma unroll
    for (int m = 32; m >= 1; m >>= 1) sq += __shfl_xor(sq, m, 64);
    __shared__ float red[4];
    if ((t & 63) == 0) red[t >> 6] = sq;
    __syncthreads();
    if (t == 0) partials[bid] = red[0] + red[1] + red[2] + red[3];
}

// ---------------------------------------------------------------------------
// K_final: loss + perplexity (f64)
// ---------------------------------------------------------------------------
__global__ void k_final(const float* __restrict__ partials,
                        const int* __restrict__ hist,
                        float* __restrict__ out) {
    int t = threadIdx.x;
    double ls = 0.0, es = 0.0;
    for (int i = t; i < 4096; i += 256) ls += (double)partials[i];
    for (int i = t; i < NE; i += 256) {
        double em = (double)hist[i] / (double)NPTS;
        es += em * log(em + 1e-10);
    }
    __shared__ double s1[256], s2[256];
    s1[t] = ls; s2[t] = es;
    __syncthreads();
    for (int s = 128; s > 0; s >>= 1) {
        if (t < s) { s1[t] += s1[t + s]; s2[t] += s2[t + s]; }
        __syncthreads();
    }
    if (t == 0) {
        out[OFF_LOSS] = (float)(s1[0] / (double)ZQ_N * 1.25);
        out[OFF_PERP] = (float)exp(-s2[0]);
    }
}

// ===========================================================================
// Fallback path (validated round-2 brute force) — used if ws_size too small
// ===========================================================================
__global__ void f_zsq(const float* __restrict__ z, float* __restrict__ zsq) {
    int gid = blockIdx.x * 256 + threadIdx.x;
    int P = gid >> 1, half = gid & 1;
    int b = P >> 10, hw = P & 1023;
    const float* zb = z + (size_t)b * (DIM * HW) + (size_t)(half * 128) * HW + hw;
    float r[8];
    #pragma unroll
    for (int j = 0; j < 8; ++j) {
        float v = zb[(size_t)j * HW];
        r[j] = mul_rn(v, v);
    }
    #pragma unroll
    for (int i = 8; i < 128; i += 8)
        #pragma unroll
        for (int j = 0; j < 8; ++j) {
            float v = zb[(size_t)(i + j) * HW];
            r[j] += mul_rn(v, v);
        }
    float s = ((r[0] + r[1]) + (r[2] + r[3])) + ((r[4] + r[5]) + (r[6] + r[7]));
    float o = __shfl_xor(s, 1, 64);
    if (half == 0) zsq[P] = s + o;
}

__global__ void f_init(int* __restrict__ hist) {
    hist[blockIdx.x * 256 + threadIdx.x] = 0;
}

#define FBP 64
#define FBC 256
#define FKC 32
__global__ __launch_bounds__(256, 2)
void f_argmin(const float* __restrict__ z, const float* __restrict__ emb,
              const float* __restrict__ zsq,
              float* __restrict__ cand_d, int* __restrict__ cand_c) {
    const int blk = blockIdx.x;
    const int pblk = blk & 255;
    const int split = blk >> 8;
    const int p0 = pblk * FBP;
    const int b = p0 >> 10;
    const int hw0 = p0 & 1023;
    const int t = threadIdx.x;
    const int tx = t & 31;
    const int ty = t >> 5;

    __shared__ __align__(16) float z_s[FBP][36];
    __shared__ __align__(16) float e_s[FBC][36];

    float bd[8];
    int bcn[8];
    #pragma unroll
    for (int i = 0; i < 8; ++i) { bd[i] = INFINITY; bcn[i] = 0x7fffffff; }
    float zsqv[8];
    #pragma unroll
    for (int i = 0; i < 8; ++i) zsqv[i] = zsq[p0 + ty * 8 + i];

    const float* zbase = z + (size_t)b * (DIM * HW) + hw0;

    for (int cc = split * 16; cc < (split + 1) * 16; ++cc) {
        float acc[8][8];
        #pragma unroll
        for (int i = 0; i < 8; ++i)
            #pragma unroll
            for (int j = 0; j < 8; ++j) acc[i][j] = 0.f;
        for (int kc = 0; kc < DIM / FKC; ++kc) {
            __syncthreads();
            {
                int i = t & 63, kk0 = t >> 6;
                #pragma unroll
                for (int r = 0; r < 8; ++r) {
                    int kk = kk0 + r * 4;
                    z_s[i][kk] = zbase[(size_t)(kc * FKC + kk) * HW + i];
                }
            }
            {
                #pragma unroll
                for (int it = 0; it < 8; ++it) {
                    int q = t + it * 256;
                    int r = q >> 3, kkq = q & 7;
                    const float4 v = *(const float4*)(emb +
                        (size_t)(cc * FBC + r) * DIM + kc * FKC + kkq * 4);
                    *(float4*)&e_s[r][kkq * 4] = v;
                }
            }
            __syncthreads();
            #pragma unroll
            for (int g = 0; g < 8; ++g) {
                float4 zf[8], ef[8];
                #pragma unroll
                for (int i = 0; i < 8; ++i)
                    zf[i] = *(const float4*)&z_s[ty * 8 + i][g * 4];
                #pragma unroll
                for (int j = 0; j < 8; ++j)
                    ef[j] = *(const float4*)&e_s[tx + j * 32][g * 4];
                #pragma unroll
                for (int i = 0; i < 8; ++i)
                    #pragma unroll
                    for (int j = 0; j < 8; ++j) {
                        float a = acc[i][j];
                        a = fmaf(zf[i].x, ef[j].x, a);
                        a = fmaf(zf[i].y, ef[j].y, a);
                        a = fmaf(zf[i].z, ef[j].z, a);
                        a = fmaf(zf[i].w, ef[j].w, a);
                        acc[i][j] = a;
                    }
            }
        }
        #pragma unroll
        for (int j = 0; j < 8; ++j) {
            int c = cc * FBC + tx + j * 32;
            #pragma unroll
            for (int i = 0; i < 8; ++i) {
                float d = zsqv[i] - 2.0f * acc[i][j];
                if (d < bd[i]) { bd[i] = d; bcn[i] = c; }
                else if (d == bd[i] && c < bcn[i]) { bcn[i] = c; }
            }
        }
    }
    #pragma unroll
    for (int i = 0; i < 8; ++i) {
        float d = bd[i];
        int c = bcn[i];
        #pragma unroll
        for (int m = 16; m >= 1; m >>= 1) {
            float od = __shfl_xor(d, m, 32);
            int oc = __shfl_xor(c, m, 32);
            if (od < d || (od == d && oc < c)) { d = od; c = oc; }
        }
        if (tx == 0) {
            int P = p0 + ty * 8 + i;
            cand_d[(size_t)split * NPTS + P] = d;
            cand_c[(size_t)split * NPTS + P] = c;
        }
    }
}

__global__ void f_pick(const float* __restrict__ cand_d,
                       const int* __restrict__ cand_c,
                       int* __restrict__ idx_i, int* __restrict__ hist,
                       float* __restrict__ out) {
    int P = blockIdx.x * 256 + threadIdx.x;
    float d0 = cand_d[P], d1 = cand_d[NPTS + P];
    int c0 = cand_c[P], c1 = cand_c[NPTS + P];
    int idx = (d1 < d0) ? c1 : c0;
    idx_i[P] = idx;
    out[OFF_IDX + P] = (float)idx;
    atomicAdd(&hist[idx], 1);
}

// ---------------------------------------------------------------------------
extern "C" void kernel_launch(void* const* d_in, const int* in_sizes, int n_in,
                              void* d_out, int out_size, void* d_ws, size_t ws_size,
                              hipStream_t stream) {
    const float* z   = (const float*)d_in[0];   // [16,256,32,32]
    const float* emb = (const float*)d_in[1];   // [8192,256]
    float* out = (float*)d_out;
    char*  ws  = (char*)d_ws;

    // ---- main-path ws layout (bytes), NEED = 20,972,032 ----
    const size_t O_ZHT  = 0;             // 8,388,608  (jobs_s after gemm)
    const size_t O_EH   = 8388608;       // 4,194,304  (jobs_f after gemm)
    const size_t O_TI   = 12582912;      // 8,388,608  tilinfo u64 [NT][NPTS]
    const size_t O_ZSQ  = 20971520;      //    65,536
    const size_t O_MARG = 21037056;      //    65,536
    const size_t O_TAU  = 21102592;      //    65,536
    const size_t O_PB   = 21168128;      //   131,072
    const size_t O_IDX  = 21299200;      //    65,536
    const size_t O_HIST = 21364736;      //    32,768
    const size_t O_PART = 21397504;      //    16,384
    const size_t O_JC   = 21413888;      //       256
    const size_t NEED   = 21414144;

    if (ws_size >= NEED) {
        float* zT = out;   // f32 [16384][256] in z_q region; overwritten by k_gather
        unsigned short* zhT   = (unsigned short*)(ws + O_ZHT);
        unsigned short* eh    = (unsigned short*)(ws + O_EH);
        unsigned long long* tilinfo = (unsigned long long*)(ws + O_TI);
        float* zsq            = (float*)(ws + O_ZSQ);
        float* marg           = (float*)(ws + O_MARG);
        float* tau            = (float*)(ws + O_TAU);
        unsigned long long* pbest = (unsigned long long*)(ws + O_PB);
        int*   idx_i          = (int*)(ws + O_IDX);
        int*   hist           = (int*)(ws + O_HIST);
        float* partials       = (float*)(ws + O_PART);
        int*   jc             = (int*)(ws + O_JC);
        // job lists alias the (dead after k_gemm_f) zhT/eh regions
        unsigned int* jobs_s  = (unsigned int*)(ws + O_ZHT);   // 2M entries cap
        unsigned int* jobs_f  = (unsigned int*)(ws + O_EH);    // 1M entries cap

        k_prep_z <<<1024, 256, 0, stream>>>(z, zT, zhT);
        k_prep_e <<<512,  256, 0, stream>>>(emb, eh);
        k_zsq    <<<128,  256, 0, stream>>>(zT, zsq, marg);
        k_init   <<<64,   256, 0, stream>>>(hist, pbest, jc);
        k_gemm_f <<<8192, 256, 0, stream>>>(zhT, eh, marg, tilinfo);
        k_flag   <<<64,   256, 0, stream>>>(tilinfo, marg, tau);
        k_filter <<<4096, 256, 0, stream>>>(tilinfo, tau, jobs_s, jobs_f, jc);
        k_rescore<<<1024, 256, 0, stream>>>(jobs_s, jobs_f, jc, zT, emb, zsq, pbest);
        k_pick   <<<64,   256, 0, stream>>>(pbest, idx_i, hist, out);
        k_gather <<<4096, 256, 0, stream>>>(z, emb, idx_i, out, partials);
        k_final  <<<1,    256, 0, stream>>>(partials, hist, out);
    } else {
        // fallback: validated round-2 brute-force path (~442KB ws)
        float* zsq      = (float*)(ws);
        int*   hist     = (int*)  (ws + 65536);
        float* cand_d   = (float*)(ws + 98304);
        int*   cand_c   = (int*)  (ws + 229376);
        int*   idx_i    = (int*)  (ws + 360448);
        float* partials = (float*)(ws + 425984);

        f_zsq   <<<128, 256, 0, stream>>>(z, zsq);
        f_init  <<<32, 256, 0, stream>>>(hist);
        f_argmin<<<512, 256, 0, stream>>>(z, emb, zsq, cand_d, cand_c);
        f_pick  <<<64, 256, 0, stream>>>(cand_d, cand_c, idx_i, hist, out);
        k_gather<<<4096, 256, 0, stream>>>(z, emb, idx_i, out, partials);
        k_final <<<1, 256, 0, stream>>>(partials, hist, out);
    }
}